// Round 2
// baseline (245.435 us; speedup 1.0000x reference)
//
#include <hip/hip_runtime.h>

// B-spline (KAN) activation, order-3, uniform grid of 12 knots -> 8 bases,
// per-channel Dense(1) contraction with W[32][8].
//
// Math: u = (x - g0)/h; d[i] = u - i.
// Level-1 bases are hats: b1[m] = max(0, 1 - |u-(m+1)|), m=0..9.
// Adjoint push-down of the W-dot through levels 2 and 3:
//   Out = sum_m b1[m] * V1[m]
//   V1[m]    = d[m]*(V2[m]-V2[m-1]) + 2*V2[m-1]
//   V2[k]    = d[k]*(W[k]-W[k-1]) + 3*W[k-1]      (W zero-extended)
// With the global 1/6 scale folded into per-thread constants:
//   P[k] = (W[k]-W[k-1])/3          (k=0..8)
//   Q[k] = W[k-1]                   (k=0..8)
//   A[m] = (W[m]-2W[m-1]+W[m-2])/6  (m=0..9)
//   v2p[m]   = fma(d[m-1], P[m-1], Q[m-1])   (== 2*V2[m-1]/6, v2p[0]=0)
//   v2diff   = fma(d[m], A[m], P[m-1])       (== (V2[m]-V2[m-1])/6)
//   V1s[m]   = fma(d[m], v2diff, v2p[m])
// ~70 VALU ops/element, all in registers; no LDS, no dynamic indexing.

#define FULL_UNROLL _Pragma("unroll")

__device__ __forceinline__ float eval_one(float x, float g0, float inv_h,
                                          const float* __restrict__ P,   // [9]
                                          const float* __restrict__ Q,   // [9]
                                          const float* __restrict__ A) { // [10]
    float u = (x - g0) * inv_h;
    float d[11];
    FULL_UNROLL
    for (int i = 0; i < 11; ++i) d[i] = u - (float)i;

    float v2p[10];             // v2p[m] = scaled 2*V2[m-1]; v2p[0] = 0
    v2p[0] = 0.0f;
    FULL_UNROLL
    for (int k = 0; k < 9; ++k) v2p[k + 1] = fmaf(d[k], P[k], Q[k]);

    float acc = 0.0f;
    FULL_UNROLL
    for (int m = 0; m < 10; ++m) {
        float pm1 = (m == 0) ? 0.0f : P[m - 1];
        float vd  = fmaf(d[m], A[m], pm1);        // scaled V2[m]-V2[m-1]
        float v1  = fmaf(d[m], vd, v2p[m]);       // scaled V1[m]
        float h   = fmaxf(1.0f - fabsf(d[m + 1]), 0.0f);  // hat b1[m]
        acc = fmaf(h, v1, acc);
    }
    return acc;
}

__global__ void kan_bspline_kernel(const float* __restrict__ x,
                                   const float* __restrict__ grid,
                                   const float* __restrict__ W,
                                   float* __restrict__ out,
                                   int n2) {
    const int tid = blockIdx.x * blockDim.x + threadIdx.x;
    // Element e = 2*tid has channel e%32 (even); the pair is (c0, c0+1).
    // Grid-stride step = 2*gridDim*blockDim elements, a multiple of 32,
    // so the channel pair is invariant across iterations.
    const int c0 = (2 * tid) & 31;

    const float g0 = grid[0];
    const float inv_h = 11.0f / (grid[11] - grid[0]);

    float P[2][9], Q[2][9], A[2][10];
    FULL_UNROLL
    for (int ch = 0; ch < 2; ++ch) {
        const float* wr = W + (c0 + ch) * 8;
        float wpad[12];  // indices -2..9 shifted by +2; zero outside 0..7
        FULL_UNROLL
        for (int j = 0; j < 12; ++j) wpad[j] = 0.0f;
        FULL_UNROLL
        for (int j = 0; j < 8; ++j) wpad[j + 2] = wr[j];
        const float sixth = 1.0f / 6.0f;
        FULL_UNROLL
        for (int k = 0; k < 9; ++k) {
            P[ch][k] = 2.0f * sixth * (wpad[k + 2] - wpad[k + 1]);
            Q[ch][k] = wpad[k + 1];
        }
        FULL_UNROLL
        for (int m = 0; m < 10; ++m) {
            A[ch][m] = sixth * (wpad[m + 2] - 2.0f * wpad[m + 1] + wpad[m]);
        }
    }

    const long long n2l = n2;
    const long long stride = (long long)gridDim.x * blockDim.x;
    const float2* __restrict__ x2 = (const float2*)x;
    float2* __restrict__ o2 = (float2*)out;

    for (long long i = tid; i < n2l; i += stride) {
        float2 xv = x2[i];
        float2 ov;
        ov.x = eval_one(xv.x, g0, inv_h, P[0], Q[0], A[0]);
        ov.y = eval_one(xv.y, g0, inv_h, P[1], Q[1], A[1]);
        o2[i] = ov;
    }
}

extern "C" void kernel_launch(void* const* d_in, const int* in_sizes, int n_in,
                              void* d_out, int out_size, void* d_ws, size_t ws_size,
                              hipStream_t stream) {
    const float* x    = (const float*)d_in[0];
    const float* grid = (const float*)d_in[1];
    const float* W    = (const float*)d_in[2];
    float* out        = (float*)d_out;

    const int n  = in_sizes[0];   // 16*256*256*32 = 33,554,432
    const int n2 = n / 2;         // float2 work-items

    const int threads = 256;
    const int blocks  = 2048;     // grid-stride; 32 iters/thread
    hipLaunchKernelGGL(kan_bspline_kernel, dim3(blocks), dim3(threads), 0, stream,
                       x, grid, W, out, n2);
}

// Round 4
// 233.479 us; speedup vs baseline: 1.0512x; 1.0512x over previous
//
#include <hip/hip_runtime.h>

// B-spline (KAN) activation, order-3, uniform 12-knot grid -> 8 bases,
// per-channel Dense(1) contraction with W[32][8].
//
// Key identity: on a uniform grid the spline output restricted to knot
// interval i (u = (x-g0)/h in [i, i+1), t = u-i) is a single cubic:
//   out = a0 + a1 t + a2 t^2 + a3 t^3
// with (w_k = W[c, i-3+k], zero-padded outside 0..7):
//   a0 = (w0 + 4 w1 + w2)/6
//   a1 = (w2 - w0)/2
//   a2 = (w0 - 2 w1 + w2)/2
//   a3 = (-w0 + 3 w1 - 3 w2 + w3)/6
// Table: [32 ch][11 intervals] float4 in LDS (5.8 KB), built once per block.
// Swizzle: float4 index es = c*11 + i + (c>>2). Within a wave the 8
// channel-groups (c0 = 4*(lane&7) spacing) then map to 8 distinct bank-quads
// ((45 q + i) mod 8, 5 coprime 8) for the dominant equal-i case; same-group
// lanes differ in i -> distinct banks for i mod 8. Residual conflicts <=2-way.
//
// Per element: ~16 VALU + 1 ds_read_b128 + masked Horner; float4 global I/O.

#define NCH 32
#define NINT 11

__global__ __launch_bounds__(256) void kan_bspline_kernel(
    const float* __restrict__ x,
    const float* __restrict__ grid,
    const float* __restrict__ W,
    float* __restrict__ out,
    int n4) {
  __shared__ float4 coef[NCH * NINT + 8];  // 360 swizzled entries

  // ---- build coefficient table (2 rounds of 256 threads) ----
  const float sixth = 1.0f / 6.0f;
  for (int e = threadIdx.x; e < NCH * NINT; e += 256) {
    int c = e / NINT;
    int i = e - c * NINT;
    float w[4];
#pragma unroll
    for (int k = 0; k < 4; ++k) {
      int j = i - 3 + k;
      w[k] = (j >= 0 && j < 8) ? W[c * 8 + j] : 0.0f;
    }
    float4 a;
    a.x = (w[0] + 4.0f * w[1] + w[2]) * sixth;
    a.y = 0.5f * (w[2] - w[0]);
    a.z = 0.5f * (w[0] - 2.0f * w[1] + w[2]);
    a.w = (w[3] - w[0]) * sixth + 0.5f * (w[1] - w[2]);
    coef[e + (c >> 2)] = a;  // swizzled store
  }
  __syncthreads();

  const float g0 = grid[0];
  const float inv_h = 11.0f / (grid[11] - grid[0]);  // = 2.5 exactly

  const float4* __restrict__ x4 = (const float4*)x;
  float4* __restrict__ o4 = (float4*)out;

  const int tid = blockIdx.x * blockDim.x + threadIdx.x;
  const int stride = gridDim.x * blockDim.x;
  // Elements 4*tid..4*tid+3 -> channels c0..c0+3; grid-stride step is
  // 4*stride elements == 0 mod 32, so the channel quad is loop-invariant.
  const int c0 = (4 * tid) & 31;
  int base[4];
#pragma unroll
  for (int k = 0; k < 4; ++k) base[k] = (c0 + k) * NINT + (c0 >> 2);

  for (int idx = tid; idx < n4; idx += stride) {
    float4 xv = x4[idx];
    float xs[4] = {xv.x, xv.y, xv.z, xv.w};
    float rs[4];
#pragma unroll
    for (int k = 0; k < 4; ++k) {
      float u = (xs[k] - g0) * inv_h;
      float fi = floorf(u);
      float fic = fminf(fmaxf(fi, 0.0f), 10.0f);
      float t = u - fic;
      int i = (int)fic;
      float4 a = coef[base[k] + i];
      float r = fmaf(fmaf(fmaf(a.w, t, a.z), t, a.y), t, a.x);
      // reference order-0 bases are half-open [g_i, g_{i+1}) -> zero outside
      rs[k] = (fi >= 0.0f && fi <= 10.0f) ? r : 0.0f;
    }
    float4 ov = make_float4(rs[0], rs[1], rs[2], rs[3]);
    o4[idx] = ov;
  }
}

extern "C" void kernel_launch(void* const* d_in, const int* in_sizes, int n_in,
                              void* d_out, int out_size, void* d_ws, size_t ws_size,
                              hipStream_t stream) {
  const float* x    = (const float*)d_in[0];
  const float* grid = (const float*)d_in[1];
  const float* W    = (const float*)d_in[2];
  float* out        = (float*)d_out;

  const int n  = in_sizes[0];  // 33,554,432
  const int n4 = n / 4;        // 8,388,608 float4 work items

  const int threads = 256;
  const int blocks  = 4096;    // 1,048,576 threads -> 8 grid-stride iters
  hipLaunchKernelGGL(kan_bspline_kernel, dim3(blocks), dim3(threads), 0, stream,
                     x, grid, W, out, n4);
}

// Round 7
// 229.453 us; speedup vs baseline: 1.0697x; 1.0175x over previous
//
#include <hip/hip_runtime.h>

// B-spline (KAN) activation, order-3, uniform 12-knot grid -> 8 bases,
// per-channel Dense(1) contraction with W[32][8].
//
// Per-interval cubic (uniform grid): u=(x-g0)/h in [i,i+1), t=u-i:
//   out = a0 + a1 t + a2 t^2 + a3 t^3
//   a0=(w0+4w1+w2)/6, a1=(w2-w0)/2, a2=(w0-2w1+w2)/2, a3=(w3-w0)/6+(w1-w2)/2
//   (w_k = W[c, i-3+k], zero outside 0..7)
// Table [32ch][11 intervals] float4 in LDS, bank-quad swizzled.
//
// Structure: ONE float4 per thread (no grid-stride loop) -> pure TLP latency
// hiding; x-load issued before the table build so HBM latency hides under
// setup; nontemporal stores keep L2/L3 for x.

#define NCH 32
#define NINT 11

typedef float vf4 __attribute__((ext_vector_type(4)));  // native vec for NT ops

__global__ __launch_bounds__(256) void kan_bspline_kernel(
    const float* __restrict__ x,
    const float* __restrict__ grid,
    const float* __restrict__ W,
    float* __restrict__ out,
    int n4) {
  __shared__ float4 coef[NCH * NINT + 8];  // 360 swizzled entries (~5.8 KB)

  const int tid = blockIdx.x * blockDim.x + threadIdx.x;
  const vf4* __restrict__ x4 = (const vf4*)x;

  // Issue the global load FIRST; its ~600-900 cy latency hides under the
  // table build + barrier below.
  vf4 xv = (tid < n4) ? x4[tid] : (vf4)(0.0f);

  // ---- build coefficient table (2 rounds of 256 threads) ----
  const float sixth = 1.0f / 6.0f;
  for (int e = threadIdx.x; e < NCH * NINT; e += 256) {
    int c = e / NINT;
    int i = e - c * NINT;
    float w[4];
#pragma unroll
    for (int k = 0; k < 4; ++k) {
      int j = i - 3 + k;
      w[k] = (j >= 0 && j < 8) ? W[c * 8 + j] : 0.0f;
    }
    float4 a;
    a.x = (w[0] + 4.0f * w[1] + w[2]) * sixth;
    a.y = 0.5f * (w[2] - w[0]);
    a.z = 0.5f * (w[0] - 2.0f * w[1] + w[2]);
    a.w = (w[3] - w[0]) * sixth + 0.5f * (w[1] - w[2]);
    coef[e + (c >> 2)] = a;  // swizzle: +c/4 makes the 8 channel-quads of a
                             // wave hit 8 distinct bank-quads at equal i
  }
  __syncthreads();

  if (tid >= n4) return;

  const float g0 = grid[0];
  const float inv_h = 11.0f / (grid[11] - grid[0]);  // = 2.5 exactly

  // Elements 4*tid..4*tid+3 -> channels c0..c0+3 (c0 = 4*tid mod 32).
  const int c0 = (4 * tid) & 31;
  int base[4];
#pragma unroll
  for (int k = 0; k < 4; ++k) base[k] = (c0 + k) * NINT + (c0 >> 2);

  float xs[4] = {xv.x, xv.y, xv.z, xv.w};
  float rs[4];
#pragma unroll
  for (int k = 0; k < 4; ++k) {
    float u = (xs[k] - g0) * inv_h;
    float fi = floorf(u);
    float fic = fminf(fmaxf(fi, 0.0f), 10.0f);
    float t = u - fic;
    int i = (int)fic;
    float4 a = coef[base[k] + i];
    float r = fmaf(fmaf(fmaf(a.w, t, a.z), t, a.y), t, a.x);
    // reference order-0 bases are half-open [g_i, g_{i+1}) -> zero outside
    rs[k] = (fi >= 0.0f && fi <= 10.0f) ? r : 0.0f;
  }

  vf4 ov;
  ov.x = rs[0]; ov.y = rs[1]; ov.z = rs[2]; ov.w = rs[3];
  vf4* __restrict__ o4 = (vf4*)out;
  __builtin_nontemporal_store(ov, &o4[tid]);  // write-once stream
}

extern "C" void kernel_launch(void* const* d_in, const int* in_sizes, int n_in,
                              void* d_out, int out_size, void* d_ws, size_t ws_size,
                              hipStream_t stream) {
  const float* x    = (const float*)d_in[0];
  const float* grid = (const float*)d_in[1];
  const float* W    = (const float*)d_in[2];
  float* out        = (float*)d_out;

  const int n  = in_sizes[0];  // 33,554,432
  const int n4 = n / 4;        // 8,388,608 float4 work items

  const int threads = 256;
  const int blocks  = (n4 + threads - 1) / threads;  // 32768, exact
  hipLaunchKernelGGL(kan_bspline_kernel, dim3(blocks), dim3(threads), 0, stream,
                     x, grid, W, out, n4);
}